// Round 5
// baseline (190.528 us; speedup 1.0000x reference)
//
#include <hip/hip_runtime.h>
#include <hip/hip_bf16.h>
#include <cstddef>

// 3-layer tanh RNN (B=8192, T=80, D=32, H=64), fused, MFMA.
// SYSTOLIC LAYER PIPELINE, register-carried recurrence (K=32).
// R16: CH=8 CHUNKS - 12 intervals (vs 22), amortizing per-interval fixed cost.
//
// R15 post-mortem: hoisting input-proj MFMAs regressed (75.4->87us) - R12's
// in-step order lets the compiler overlap step jj+1's input MFMAs with step
// jj's serial tail; hoisting removed that. Step body below is R12 VERBATIM.
// R12 accounting: 181k cyc / 22 intervals = 8.2k cyc/interval, but per-wave
// issue work is only ~2-3k => each interval carries ~3-4k cyc of fixed
// overhead F (barrier convergence, wave imbalance, drains). Model:
// wall = N_int*(F + CH*s). CH=8 cuts N_int 22->12, halving total F.
//
// Structure:
//   - wave wv = layer wv; interval m (0..11): t = 8*(m-wv) .. +7; ONE barrier
//     per interval; LDS ring hb[layer<2][t&15][16][72] (73728 B, 2 blk/CU ok):
//     reader slots (lt0-8..lt0-1)&15, writer (lt0..+7)&15, upstream writer
//     (lt0+8..+15)&15 - pairwise disjoint mod 16;
//   - recurrence register-carried at K=32 via k-permuted Whh frags
//     (slot i = h[32h+16(i>>2)+4q+(i&3)], bijection folded into weight gather);
//   - wave-0 x double-buffered raw (fx4) 8 t's deep, packed at interval top,
//     refill issued after packing, consumed next interval.
// MFMA maps (verified R2-R11):
//   K=32 A: A[m=lane&15][k=8q+i]; B: B[k=8q+i][n=lane&15]  (q=lane>>4)
//   16x16 D: D[row=4q+r][col=lane&15]
// tanh via exp2 (bias pre-scaled by 2*log2e) - numerics identical to R12.

typedef __attribute__((ext_vector_type(8))) short s16x8;
typedef __attribute__((ext_vector_type(4))) short s16x4;
typedef __attribute__((ext_vector_type(4))) float fx4;

#define MFMA32(A, B, C) __builtin_amdgcn_mfma_f32_16x16x32_bf16((A), (B), (C), 0, 0, 0)

#if __has_builtin(__builtin_amdgcn_exp2f)
#define EXP2F(x) __builtin_amdgcn_exp2f(x)
#else
#define EXP2F(x) exp2f(x)
#endif
#if __has_builtin(__builtin_amdgcn_rcpf)
#define RCPF(x) __builtin_amdgcn_rcpf(x)
#else
#define RCPF(x) (1.0f / (x))
#endif

static constexpr float K2LOG2E = 2.8853900817779268f;  // 2*log2(e)

__device__ __forceinline__ short f2bf(float f) {  // RNE float->bf16 (weights, one-time)
  union { float f; unsigned u; } v; v.f = f;
  unsigned r = v.u + 0x7FFFu + ((v.u >> 16) & 1u);
  return (short)(r >> 16);
}
__device__ __forceinline__ float bf2f(short s) {
  union { unsigned u; float f; } v; v.u = ((unsigned)(unsigned short)s) << 16;
  return v.f;
}
__device__ __forceinline__ unsigned pk2bf(float a, float b) {  // v_cvt_pk_bf16_f32
  float2 t; t.x = a; t.y = b;
  union { __hip_bfloat162 h; unsigned u; } c;
  c.h = __float22bfloat162_rn(t);
  return c.u;
}

__device__ __forceinline__ s16x8 wfragA32(const float* W, int ncols, int row, int col0) {
  const float* p = W + row * ncols + col0;
  s16x8 r;
#pragma unroll
  for (int i = 0; i < 8; ++i) r[i] = f2bf(p[i]);
  return r;
}

// k-permuted Whh A-frag for the K=32 register-carried recurrence (half h=0,1):
// slot i  <-  Whh[row][ 32h + 16*(i>>2) + 4q + (i&3) ]
__device__ __forceinline__ s16x8 wfragWhh32(const float* W, int row, int q, int h) {
  const float* p = W + row * 64 + 32 * h + 4 * q;
  s16x8 r;
#pragma unroll
  for (int i = 0; i < 4; ++i) r[i] = f2bf(p[i]);
#pragma unroll
  for (int i = 0; i < 4; ++i) r[4 + i] = f2bf(p[16 + i]);
  return r;
}

// tanh(acc + bias) (bias pre-scaled by 2*log2e) -> packed bf16.
__device__ __forceinline__ s16x4 tanh_pack(fx4 acc, const float* bs) {
  float h[4];
#pragma unroll
  for (int r = 0; r < 4; ++r) {
    float e = EXP2F(__builtin_fmaf(acc[r], K2LOG2E, bs[r]));
    h[r] = __builtin_fmaf(-2.f, RCPF(e + 1.f), 1.f);
  }
  union { unsigned u[2]; s16x4 v; } p;
  p.u[0] = pk2bf(h[0], h[1]);
  p.u[1] = pk2bf(h[2], h[3]);
  return p.v;
}

union U8 { s16x8 v; s16x4 h[2]; };

__global__ __launch_bounds__(192, 2) void rnn3_ch8(
    const float* __restrict__ x,
    const float* __restrict__ Wih0, const float* __restrict__ Whh0,
    const float* __restrict__ bih0, const float* __restrict__ bhh0,
    const float* __restrict__ Wih1, const float* __restrict__ Whh1,
    const float* __restrict__ bih1, const float* __restrict__ bhh1,
    const float* __restrict__ Wih2, const float* __restrict__ Whh2,
    const float* __restrict__ bih2, const float* __restrict__ bhh2,
    const float* __restrict__ Wfc, const float* __restrict__ bfc,
    float* __restrict__ out)
{
  __shared__ __align__(16) short hb[2][16][16][72];  // [layer<2][t&15][batch][j], 73728 B

  const int tid = threadIdx.x;
  const int wv  = __builtin_amdgcn_readfirstlane(tid >> 6);  // 0..2 == layer
  const int ln  = tid & 63;
  const int q   = ln >> 4;        // K=32 k-quad / D row-quad
  const int m15 = ln & 15;
  const int bbase = (int)blockIdx.x * 16;

  // ---------- this wave's layer parameters ----------
  const float* Wih = (wv == 0) ? Wih0 : (wv == 1) ? Wih1 : Wih2;
  const float* Whh = (wv == 0) ? Whh0 : (wv == 1) ? Whh1 : Whh2;
  const float* bi  = (wv == 0) ? bih0 : (wv == 1) ? bih1 : bih2;
  const float* bh  = (wv == 0) ? bhh0 : (wv == 1) ? bhh1 : bhh2;
  const int kin = (wv == 0) ? 32 : 64;

  // ---------- weights (VGPR-resident) ----------
  s16x8 wiA[4], wiB[4];
  s16x8 wh32[4][2];
  const s16x8 z8 = {0, 0, 0, 0, 0, 0, 0, 0};
#pragma unroll
  for (int t4 = 0; t4 < 4; ++t4) {
    const int row = 16 * t4 + m15;
    wiA[t4] = wfragA32(Wih, kin, row, 8 * q);
    wiB[t4] = wv ? wfragA32(Wih, 64, row, 32 + 8 * q) : z8;   // layer 0: K=32 only
    wh32[t4][0] = wfragWhh32(Whh, row, q, 0);
    wh32[t4][1] = wfragWhh32(Whh, row, q, 1);
  }

  // ---------- biases pre-scaled; lane's j = 16*t4 + 4*q + r ----------
  float bsc[4][4];
#pragma unroll
  for (int t4 = 0; t4 < 4; ++t4)
#pragma unroll
    for (int r = 0; r < 4; ++r) {
      const int j = 16 * t4 + 4 * q + r;
      bsc[t4][r] = (bi[j] + bh[j]) * K2LOG2E;
    }

  const fx4 z4 = {0.f, 0.f, 0.f, 0.f};
  U8 hA, hB;                       // own state h_wv(t-1): hA=(j 0..31), hB=(j 32..63)
  hA.v = z8; hB.v = z8;

  // ---------- wave-0 x buffer: 8 t's of this interval (raw fx4) ----------
  const float* xr = x + (size_t)(bbase + m15) * (80 * 32) + 8 * q;
  fx4 xb0[8], xb1[8];
  if (wv == 0) {
#pragma unroll
    for (int jj = 0; jj < 8; ++jj) {          // preload t = 0..7
      xb0[jj] = *(const fx4*)(xr + jj * 32);
      xb1[jj] = *(const fx4*)(xr + jj * 32 + 4);
    }
  }

  for (int m = 0; m < 12; ++m) {
    const int lt0 = 8 * (m - wv);             // first t of this interval
    if (0 <= lt0 && lt0 <= 72) {              // wave-uniform
      // ---- interval top: gather all 8 inputs ----
      s16x8 inA[8], inB[8];
      if (wv == 0) {
#pragma unroll
        for (int jj = 0; jj < 8; ++jj) {
          union { unsigned u[4]; s16x8 v; } xp;
          xp.u[0] = pk2bf(xb0[jj][0], xb0[jj][1]);
          xp.u[1] = pk2bf(xb0[jj][2], xb0[jj][3]);
          xp.u[2] = pk2bf(xb1[jj][0], xb1[jj][1]);
          xp.u[3] = pk2bf(xb1[jj][2], xb1[jj][3]);
          inA[jj] = xp.v; inB[jj] = z8;
        }
        // refill for next interval (t = lt0+8 .. lt0+15, clamped); issued now,
        // consumed at NEXT interval top -> full interval to land
#pragma unroll
        for (int jj = 0; jj < 8; ++jj) {
          const int tt = (lt0 + 8 + jj <= 79) ? lt0 + 8 + jj : 79;
          xb0[jj] = *(const fx4*)(xr + tt * 32);
          xb1[jj] = *(const fx4*)(xr + tt * 32 + 4);
        }
      } else {
#pragma unroll
        for (int jj = 0; jj < 8; ++jj) {
          const short* up = &hb[wv - 1][(lt0 + jj) & 15][m15][8 * q];
          inA[jj] = *(const s16x8*)(up);
          inB[jj] = *(const s16x8*)(up + 32);
        }
      }
      // ---- 8 sequential steps (R12-verbatim step body) ----
#pragma unroll
      for (int jj = 0; jj < 8; ++jj) {
        const int st = (lt0 + jj) & 15;
        fx4 acc[4];
#pragma unroll
        for (int t4 = 0; t4 < 4; ++t4) acc[t4] = MFMA32(wiA[t4], inA[jj], z4);
        if (wv) {
#pragma unroll
          for (int t4 = 0; t4 < 4; ++t4) acc[t4] = MFMA32(wiB[t4], inB[jj], acc[t4]);
        }
#pragma unroll
        for (int t4 = 0; t4 < 4; ++t4) acc[t4] = MFMA32(wh32[t4][0], hA.v, acc[t4]);
#pragma unroll
        for (int t4 = 0; t4 < 4; ++t4) acc[t4] = MFMA32(wh32[t4][1], hB.v, acc[t4]);
        // tanh -> new own state + LDS publish for downstream (layers 0,1 only)
        U8 nA, nB;
#pragma unroll
        for (int t4 = 0; t4 < 4; ++t4) {
          s16x4 hv = tanh_pack(acc[t4], bsc[t4]);
          if (t4 < 2) nA.h[t4] = hv; else nB.h[t4 - 2] = hv;
          if (wv < 2) {
            *(s16x4*)(&hb[wv][st][m15][4 * q + 16 * t4]) = hv;
          }
        }
        hA = nA; hB = nB;
      }
    }
    __syncthreads();                          // ONE barrier per 8-step interval
  }

  // ---------- FC head: wave 2's state == h2(79), j = 16*kf + 4*q + i ----------
  if (wv == 2) {
    float sv = 0.f;
#pragma unroll
    for (int kf = 0; kf < 4; ++kf) {
      const s16x4 hh = (kf < 2) ? hA.h[kf] : hB.h[kf - 2];
#pragma unroll
      for (int i = 0; i < 4; ++i)
        sv += bf2f(hh[i]) * Wfc[16 * kf + 4 * q + i];
    }
    sv += __shfl_xor(sv, 16, 64);
    sv += __shfl_xor(sv, 32, 64);
    if (ln < 16) out[bbase + ln] = sv + bfc[0];
  }
}

extern "C" void kernel_launch(void* const* d_in, const int* in_sizes, int n_in,
                              void* d_out, int out_size, void* d_ws, size_t ws_size,
                              hipStream_t stream) {
  const float* x    = (const float*)d_in[0];
  const float* Wih0 = (const float*)d_in[1];
  const float* Whh0 = (const float*)d_in[2];
  const float* bih0 = (const float*)d_in[3];
  const float* bhh0 = (const float*)d_in[4];
  const float* Wih1 = (const float*)d_in[5];
  const float* Whh1 = (const float*)d_in[6];
  const float* bih1 = (const float*)d_in[7];
  const float* bhh1 = (const float*)d_in[8];
  const float* Wih2 = (const float*)d_in[9];
  const float* Whh2 = (const float*)d_in[10];
  const float* bih2 = (const float*)d_in[11];
  const float* bhh2 = (const float*)d_in[12];
  const float* Wfc  = (const float*)d_in[13];
  const float* bfc  = (const float*)d_in[14];

  // 512 blocks x 192 thr (3 waves = 3 pipelined layers), 16 batch rows/block:
  // 2 blocks/CU, 1.5 waves/SIMD (R12 config - best measured).
  rnn3_ch8<<<dim3(512), dim3(192), 0, stream>>>(
      x, Wih0, Whh0, bih0, bhh0, Wih1, Whh1, bih1, bhh1,
      Wih2, Whh2, bih2, bhh2, Wfc, bfc, (float*)d_out);
}

// Round 6
// 188.144 us; speedup vs baseline: 1.0127x; 1.0127x over previous
//
#include <hip/hip_runtime.h>
#include <hip/hip_bf16.h>
#include <cstddef>

// 3-layer tanh RNN (B=8192, T=80, D=32, H=64), fused, MFMA.
// SYSTOLIC LAYER PIPELINE, 4-STEP CHUNKS, register-carried recurrence (K=32).
// R17: DEFERRED LDS PUBLISH - serial step section carries zero LDS traffic.
//
// R16 fit (two-point CH=4/CH=8): wall = (80+2CH)*s + N_int*F with s~1.96k cyc,
// F~0.38k. Barriers cheap; chunk tuning exhausted; the wall is s, ~2.8x the
// per-SIMD issue work (~700/step) => per-step serial path dominated by
// wh0->wh1 dep MFMAs + tanh chain + tanh ISSUE (~370cyc/wave), with only
// step jj+1's input MFMAs as overlap material (R15: hoisting them away hurt).
// This round: remove the per-step ds_write publishes (+addr math) from the
// serial section - readers only consume after the next barrier, so all 16
// publishes batch at interval end, overlapping the barrier drain.
// Math is BIT-IDENTICAL to R12 (best measured, 75.4us).
//
// Structure (R12):
//   - wave wv = layer wv; interval m (0..21): t = 4*(m-wv)..+3; ONE barrier
//     per interval; LDS ring hb[layer<2][t&7][16][72] (36864 B);
//     reader slots (lt0-4..lt0-1)&7, writer (lt0..+3)&7, upstream (lt0+4..+7)&7
//     - pairwise disjoint mod 8;
//   - recurrence register-carried at K=32 via k-permuted Whh frags
//     (slot i = h[32h+16(i>>2)+4q+(i&3)], bijection folded into weight gather);
//   - wave-0 x double-buffered raw (fx4), packed at interval top, refill
//     issued after packing, consumed next interval.
// MFMA maps (verified R2-R11):
//   K=32 A: A[m=lane&15][k=8q+i]; B: B[k=8q+i][n=lane&15]  (q=lane>>4)
//   16x16 D: D[row=4q+r][col=lane&15]
// tanh via exp2 (bias pre-scaled by 2*log2e).

typedef __attribute__((ext_vector_type(8))) short s16x8;
typedef __attribute__((ext_vector_type(4))) short s16x4;
typedef __attribute__((ext_vector_type(4))) float fx4;

#define MFMA32(A, B, C) __builtin_amdgcn_mfma_f32_16x16x32_bf16((A), (B), (C), 0, 0, 0)

#if __has_builtin(__builtin_amdgcn_exp2f)
#define EXP2F(x) __builtin_amdgcn_exp2f(x)
#else
#define EXP2F(x) exp2f(x)
#endif
#if __has_builtin(__builtin_amdgcn_rcpf)
#define RCPF(x) __builtin_amdgcn_rcpf(x)
#else
#define RCPF(x) (1.0f / (x))
#endif

static constexpr float K2LOG2E = 2.8853900817779268f;  // 2*log2(e)

__device__ __forceinline__ short f2bf(float f) {  // RNE float->bf16 (weights, one-time)
  union { float f; unsigned u; } v; v.f = f;
  unsigned r = v.u + 0x7FFFu + ((v.u >> 16) & 1u);
  return (short)(r >> 16);
}
__device__ __forceinline__ float bf2f(short s) {
  union { unsigned u; float f; } v; v.u = ((unsigned)(unsigned short)s) << 16;
  return v.f;
}
__device__ __forceinline__ unsigned pk2bf(float a, float b) {  // v_cvt_pk_bf16_f32
  float2 t; t.x = a; t.y = b;
  union { __hip_bfloat162 h; unsigned u; } c;
  c.h = __float22bfloat162_rn(t);
  return c.u;
}

__device__ __forceinline__ s16x8 wfragA32(const float* W, int ncols, int row, int col0) {
  const float* p = W + row * ncols + col0;
  s16x8 r;
#pragma unroll
  for (int i = 0; i < 8; ++i) r[i] = f2bf(p[i]);
  return r;
}

// k-permuted Whh A-frag for the K=32 register-carried recurrence (half h=0,1):
// slot i  <-  Whh[row][ 32h + 16*(i>>2) + 4q + (i&3) ]
__device__ __forceinline__ s16x8 wfragWhh32(const float* W, int row, int q, int h) {
  const float* p = W + row * 64 + 32 * h + 4 * q;
  s16x8 r;
#pragma unroll
  for (int i = 0; i < 4; ++i) r[i] = f2bf(p[i]);
#pragma unroll
  for (int i = 0; i < 4; ++i) r[4 + i] = f2bf(p[16 + i]);
  return r;
}

// tanh(acc + bias) (bias pre-scaled by 2*log2e) -> packed bf16.
__device__ __forceinline__ s16x4 tanh_pack(fx4 acc, const float* bs) {
  float h[4];
#pragma unroll
  for (int r = 0; r < 4; ++r) {
    float e = EXP2F(__builtin_fmaf(acc[r], K2LOG2E, bs[r]));
    h[r] = __builtin_fmaf(-2.f, RCPF(e + 1.f), 1.f);
  }
  union { unsigned u[2]; s16x4 v; } p;
  p.u[0] = pk2bf(h[0], h[1]);
  p.u[1] = pk2bf(h[2], h[3]);
  return p.v;
}

union U8 { s16x8 v; s16x4 h[2]; };

__global__ __launch_bounds__(192, 2) void rnn3_defer(
    const float* __restrict__ x,
    const float* __restrict__ Wih0, const float* __restrict__ Whh0,
    const float* __restrict__ bih0, const float* __restrict__ bhh0,
    const float* __restrict__ Wih1, const float* __restrict__ Whh1,
    const float* __restrict__ bih1, const float* __restrict__ bhh1,
    const float* __restrict__ Wih2, const float* __restrict__ Whh2,
    const float* __restrict__ bih2, const float* __restrict__ bhh2,
    const float* __restrict__ Wfc, const float* __restrict__ bfc,
    float* __restrict__ out)
{
  __shared__ __align__(16) short hb[2][8][16][72];  // [layer<2][t&7][batch][j], 36864 B

  const int tid = threadIdx.x;
  const int wv  = __builtin_amdgcn_readfirstlane(tid >> 6);  // 0..2 == layer
  const int ln  = tid & 63;
  const int q   = ln >> 4;        // K=32 k-quad / D row-quad
  const int m15 = ln & 15;
  const int bbase = (int)blockIdx.x * 16;

  // ---------- this wave's layer parameters ----------
  const float* Wih = (wv == 0) ? Wih0 : (wv == 1) ? Wih1 : Wih2;
  const float* Whh = (wv == 0) ? Whh0 : (wv == 1) ? Whh1 : Whh2;
  const float* bi  = (wv == 0) ? bih0 : (wv == 1) ? bih1 : bih2;
  const float* bh  = (wv == 0) ? bhh0 : (wv == 1) ? bhh1 : bhh2;
  const int kin = (wv == 0) ? 32 : 64;

  // ---------- weights (VGPR-resident) ----------
  s16x8 wiA[4], wiB[4];
  s16x8 wh32[4][2];
  const s16x8 z8 = {0, 0, 0, 0, 0, 0, 0, 0};
#pragma unroll
  for (int t4 = 0; t4 < 4; ++t4) {
    const int row = 16 * t4 + m15;
    wiA[t4] = wfragA32(Wih, kin, row, 8 * q);
    wiB[t4] = wv ? wfragA32(Wih, 64, row, 32 + 8 * q) : z8;   // layer 0: K=32 only
    wh32[t4][0] = wfragWhh32(Whh, row, q, 0);
    wh32[t4][1] = wfragWhh32(Whh, row, q, 1);
  }

  // ---------- biases pre-scaled; lane's j = 16*t4 + 4*q + r ----------
  float bsc[4][4];
#pragma unroll
  for (int t4 = 0; t4 < 4; ++t4)
#pragma unroll
    for (int r = 0; r < 4; ++r) {
      const int j = 16 * t4 + 4 * q + r;
      bsc[t4][r] = (bi[j] + bh[j]) * K2LOG2E;
    }

  const fx4 z4 = {0.f, 0.f, 0.f, 0.f};
  U8 hA, hB;                       // own state h_wv(t-1): hA=(j 0..31), hB=(j 32..63)
  hA.v = z8; hB.v = z8;

  // ---------- wave-0 x buffer: 4 t's of this interval (raw fx4) ----------
  const float* xr = x + (size_t)(bbase + m15) * (80 * 32) + 8 * q;
  fx4 xb0[4], xb1[4];
  if (wv == 0) {
#pragma unroll
    for (int jj = 0; jj < 4; ++jj) {          // preload t = 0..3
      xb0[jj] = *(const fx4*)(xr + jj * 32);
      xb1[jj] = *(const fx4*)(xr + jj * 32 + 4);
    }
  }

  for (int m = 0; m < 22; ++m) {
    const int lt0 = 4 * (m - wv);             // first t of this interval
    if (0 <= lt0 && lt0 <= 76) {              // wave-uniform
      // ---- interval top: gather all 4 inputs ----
      s16x8 inA[4], inB[4];
      if (wv == 0) {
#pragma unroll
        for (int jj = 0; jj < 4; ++jj) {
          union { unsigned u[4]; s16x8 v; } xp;
          xp.u[0] = pk2bf(xb0[jj][0], xb0[jj][1]);
          xp.u[1] = pk2bf(xb0[jj][2], xb0[jj][3]);
          xp.u[2] = pk2bf(xb1[jj][0], xb1[jj][1]);
          xp.u[3] = pk2bf(xb1[jj][2], xb1[jj][3]);
          inA[jj] = xp.v; inB[jj] = z8;
        }
        // refill for next interval (t = lt0+4 .. lt0+7, clamped); issued now,
        // consumed at NEXT interval top -> full interval to land
#pragma unroll
        for (int jj = 0; jj < 4; ++jj) {
          const int tt = (lt0 + 4 + jj <= 79) ? lt0 + 4 + jj : 79;
          xb0[jj] = *(const fx4*)(xr + tt * 32);
          xb1[jj] = *(const fx4*)(xr + tt * 32 + 4);
        }
      } else {
#pragma unroll
        for (int jj = 0; jj < 4; ++jj) {
          const short* up = &hb[wv - 1][(lt0 + jj) & 7][m15][8 * q];
          inA[jj] = *(const s16x8*)(up);
          inB[jj] = *(const s16x8*)(up + 32);
        }
      }
      // ---- 4 sequential steps (R12-verbatim math; publish DEFERRED) ----
      s16x4 sv[4][4];                          // per-step tanh'd tiles (regs)
#pragma unroll
      for (int jj = 0; jj < 4; ++jj) {
        fx4 acc[4];
#pragma unroll
        for (int t4 = 0; t4 < 4; ++t4) acc[t4] = MFMA32(wiA[t4], inA[jj], z4);
        if (wv) {
#pragma unroll
          for (int t4 = 0; t4 < 4; ++t4) acc[t4] = MFMA32(wiB[t4], inB[jj], acc[t4]);
        }
#pragma unroll
        for (int t4 = 0; t4 < 4; ++t4) acc[t4] = MFMA32(wh32[t4][0], hA.v, acc[t4]);
#pragma unroll
        for (int t4 = 0; t4 < 4; ++t4) acc[t4] = MFMA32(wh32[t4][1], hB.v, acc[t4]);
        // tanh -> new own state; NO LDS traffic inside the serial section
        U8 nA, nB;
#pragma unroll
        for (int t4 = 0; t4 < 4; ++t4) {
          s16x4 hv = tanh_pack(acc[t4], bsc[t4]);
          sv[jj][t4] = hv;
          if (t4 < 2) nA.h[t4] = hv; else nB.h[t4 - 2] = hv;
        }
        hA = nA; hB = nB;
      }
      // ---- batched publish for downstream (layers 0,1 only): overlaps the
      // barrier drain; readers consume only after the next __syncthreads ----
      if (wv < 2) {
#pragma unroll
        for (int jj = 0; jj < 4; ++jj) {
          short* wb = &hb[wv][(lt0 + jj) & 7][m15][4 * q];
#pragma unroll
          for (int t4 = 0; t4 < 4; ++t4)
            *(s16x4*)(wb + 16 * t4) = sv[jj][t4];
        }
      }
    }
    __syncthreads();                          // ONE barrier per 4-step interval
  }

  // ---------- FC head: wave 2's state == h2(79), j = 16*kf + 4*q + i ----------
  if (wv == 2) {
    float sv2 = 0.f;
#pragma unroll
    for (int kf = 0; kf < 4; ++kf) {
      const s16x4 hh = (kf < 2) ? hA.h[kf] : hB.h[kf - 2];
#pragma unroll
      for (int i = 0; i < 4; ++i)
        sv2 += bf2f(hh[i]) * Wfc[16 * kf + 4 * q + i];
    }
    sv2 += __shfl_xor(sv2, 16, 64);
    sv2 += __shfl_xor(sv2, 32, 64);
    if (ln < 16) out[bbase + ln] = sv2 + bfc[0];
  }
}

extern "C" void kernel_launch(void* const* d_in, const int* in_sizes, int n_in,
                              void* d_out, int out_size, void* d_ws, size_t ws_size,
                              hipStream_t stream) {
  const float* x    = (const float*)d_in[0];
  const float* Wih0 = (const float*)d_in[1];
  const float* Whh0 = (const float*)d_in[2];
  const float* bih0 = (const float*)d_in[3];
  const float* bhh0 = (const float*)d_in[4];
  const float* Wih1 = (const float*)d_in[5];
  const float* Whh1 = (const float*)d_in[6];
  const float* bih1 = (const float*)d_in[7];
  const float* bhh1 = (const float*)d_in[8];
  const float* Wih2 = (const float*)d_in[9];
  const float* Whh2 = (const float*)d_in[10];
  const float* bih2 = (const float*)d_in[11];
  const float* bhh2 = (const float*)d_in[12];
  const float* Wfc  = (const float*)d_in[13];
  const float* bfc  = (const float*)d_in[14];

  // 512 blocks x 192 thr (3 waves = 3 pipelined layers), 16 batch rows/block:
  // 2 blocks/CU, 1.5 waves/SIMD (R12 config - best measured).
  rnn3_defer<<<dim3(512), dim3(192), 0, stream>>>(
      x, Wih0, Whh0, bih0, bhh0, Wih1, Whh1, bih1, bhh1,
      Wih2, Whh2, bih2, bhh2, Wfc, bfc, (float*)d_out);
}

// Round 7
// 185.015 us; speedup vs baseline: 1.0298x; 1.0169x over previous
//
#include <hip/hip_runtime.h>
#include <hip/hip_bf16.h>
#include <cstddef>

// 3-layer tanh RNN (B=8192, T=80, D=32, H=64), fused, MFMA.
// SYSTOLIC LAYER PIPELINE, 4-STEP CHUNKS, register-carried recurrence (K=32).
// R18: PAIRED-RCP TANH - two values share one v_rcp_f32 (8 rcp/step vs 16).
//
// Model (R12-R17): wall = per-step s~1.9k cyc; barriers cheap (F~0.4k);
// step body compiler-optimal (R15/R17 probes). VALUBusy/MfmaUtil = 2.6 only
// reconciles with instruction counts if trans ops (v_exp_f32/v_rcp_f32) cost
// ~12-16 cyc/wave64 -> the 32 trans/step are ~half the wave's issue. R14's
// LUT failure was a bad trade (equal VALU + 10M bank conflicts), not evidence
// trans is cheap. This round: rp=rcp(a0*a1); 1/a0=a1*rp; 1/a1=a0*rp -
// trades 1 trans for 3 full-rate muls per pair. Numerics: rcp ~1ulp =>
// induced error ~5e-7, far below bf16 state quantum.
//
// Structure (R17 = R12 + deferred publish, best measured 74.3us):
//   - wave wv = layer wv; interval m (0..21): t = 4*(m-wv)..+3; ONE barrier
//     per interval; LDS ring hb[layer<2][t&7][16][72] (36864 B);
//     reader slots (lt0-4..lt0-1)&7, writer (lt0..+3)&7, upstream (lt0+4..+7)&7
//     - pairwise disjoint mod 8;
//   - recurrence register-carried at K=32 via k-permuted Whh frags
//     (slot i = h[32h+16(i>>2)+4q+(i&3)], bijection folded into weight gather);
//   - wave-0 x double-buffered raw (fx4), packed at interval top, refill
//     issued after packing, consumed next interval;
//   - publishes deferred to interval end (overlap barrier drain).
// MFMA maps (verified R2-R11):
//   K=32 A: A[m=lane&15][k=8q+i]; B: B[k=8q+i][n=lane&15]  (q=lane>>4)
//   16x16 D: D[row=4q+r][col=lane&15]
// tanh via exp2 (bias pre-scaled by 2*log2e) + paired rcp.

typedef __attribute__((ext_vector_type(8))) short s16x8;
typedef __attribute__((ext_vector_type(4))) short s16x4;
typedef __attribute__((ext_vector_type(4))) float fx4;

#define MFMA32(A, B, C) __builtin_amdgcn_mfma_f32_16x16x32_bf16((A), (B), (C), 0, 0, 0)

#if __has_builtin(__builtin_amdgcn_exp2f)
#define EXP2F(x) __builtin_amdgcn_exp2f(x)
#else
#define EXP2F(x) exp2f(x)
#endif
#if __has_builtin(__builtin_amdgcn_rcpf)
#define RCPF(x) __builtin_amdgcn_rcpf(x)
#else
#define RCPF(x) (1.0f / (x))
#endif

static constexpr float K2LOG2E = 2.8853900817779268f;  // 2*log2(e)

__device__ __forceinline__ short f2bf(float f) {  // RNE float->bf16 (weights, one-time)
  union { float f; unsigned u; } v; v.f = f;
  unsigned r = v.u + 0x7FFFu + ((v.u >> 16) & 1u);
  return (short)(r >> 16);
}
__device__ __forceinline__ float bf2f(short s) {
  union { unsigned u; float f; } v; v.u = ((unsigned)(unsigned short)s) << 16;
  return v.f;
}
__device__ __forceinline__ unsigned pk2bf(float a, float b) {  // v_cvt_pk_bf16_f32
  float2 t; t.x = a; t.y = b;
  union { __hip_bfloat162 h; unsigned u; } c;
  c.h = __float22bfloat162_rn(t);
  return c.u;
}

__device__ __forceinline__ s16x8 wfragA32(const float* W, int ncols, int row, int col0) {
  const float* p = W + row * ncols + col0;
  s16x8 r;
#pragma unroll
  for (int i = 0; i < 8; ++i) r[i] = f2bf(p[i]);
  return r;
}

// k-permuted Whh A-frag for the K=32 register-carried recurrence (half h=0,1):
// slot i  <-  Whh[row][ 32h + 16*(i>>2) + 4q + (i&3) ]
__device__ __forceinline__ s16x8 wfragWhh32(const float* W, int row, int q, int h) {
  const float* p = W + row * 64 + 32 * h + 4 * q;
  s16x8 r;
#pragma unroll
  for (int i = 0; i < 4; ++i) r[i] = f2bf(p[i]);
#pragma unroll
  for (int i = 0; i < 4; ++i) r[4 + i] = f2bf(p[16 + i]);
  return r;
}

// tanh(acc + bias) (bias pre-scaled by 2*log2e) -> packed bf16.
// PAIRED RCP: rp = rcp(a0*a1); 1/a0 = a1*rp; 1/a1 = a0*rp  (8 rcp/step vs 16)
__device__ __forceinline__ s16x4 tanh_pack(fx4 acc, const float* bs) {
  float a[4], h[4];
#pragma unroll
  for (int r = 0; r < 4; ++r)
    a[r] = EXP2F(__builtin_fmaf(acc[r], K2LOG2E, bs[r])) + 1.f;
#pragma unroll
  for (int pr = 0; pr < 2; ++pr) {
    float p  = a[2 * pr] * a[2 * pr + 1];
    float rp = RCPF(p);
    float m0 = a[2 * pr + 1] * rp;     // = 1/a0
    float m1 = a[2 * pr] * rp;         // = 1/a1
    h[2 * pr]     = __builtin_fmaf(-2.f, m0, 1.f);
    h[2 * pr + 1] = __builtin_fmaf(-2.f, m1, 1.f);
  }
  union { unsigned u[2]; s16x4 v; } pk;
  pk.u[0] = pk2bf(h[0], h[1]);
  pk.u[1] = pk2bf(h[2], h[3]);
  return pk.v;
}

union U8 { s16x8 v; s16x4 h[2]; };

__global__ __launch_bounds__(192, 2) void rnn3_prcp(
    const float* __restrict__ x,
    const float* __restrict__ Wih0, const float* __restrict__ Whh0,
    const float* __restrict__ bih0, const float* __restrict__ bhh0,
    const float* __restrict__ Wih1, const float* __restrict__ Whh1,
    const float* __restrict__ bih1, const float* __restrict__ bhh1,
    const float* __restrict__ Wih2, const float* __restrict__ Whh2,
    const float* __restrict__ bih2, const float* __restrict__ bhh2,
    const float* __restrict__ Wfc, const float* __restrict__ bfc,
    float* __restrict__ out)
{
  __shared__ __align__(16) short hb[2][8][16][72];  // [layer<2][t&7][batch][j], 36864 B

  const int tid = threadIdx.x;
  const int wv  = __builtin_amdgcn_readfirstlane(tid >> 6);  // 0..2 == layer
  const int ln  = tid & 63;
  const int q   = ln >> 4;        // K=32 k-quad / D row-quad
  const int m15 = ln & 15;
  const int bbase = (int)blockIdx.x * 16;

  // ---------- this wave's layer parameters ----------
  const float* Wih = (wv == 0) ? Wih0 : (wv == 1) ? Wih1 : Wih2;
  const float* Whh = (wv == 0) ? Whh0 : (wv == 1) ? Whh1 : Whh2;
  const float* bi  = (wv == 0) ? bih0 : (wv == 1) ? bih1 : bih2;
  const float* bh  = (wv == 0) ? bhh0 : (wv == 1) ? bhh1 : bhh2;
  const int kin = (wv == 0) ? 32 : 64;

  // ---------- weights (VGPR-resident) ----------
  s16x8 wiA[4], wiB[4];
  s16x8 wh32[4][2];
  const s16x8 z8 = {0, 0, 0, 0, 0, 0, 0, 0};
#pragma unroll
  for (int t4 = 0; t4 < 4; ++t4) {
    const int row = 16 * t4 + m15;
    wiA[t4] = wfragA32(Wih, kin, row, 8 * q);
    wiB[t4] = wv ? wfragA32(Wih, 64, row, 32 + 8 * q) : z8;   // layer 0: K=32 only
    wh32[t4][0] = wfragWhh32(Whh, row, q, 0);
    wh32[t4][1] = wfragWhh32(Whh, row, q, 1);
  }

  // ---------- biases pre-scaled; lane's j = 16*t4 + 4*q + r ----------
  float bsc[4][4];
#pragma unroll
  for (int t4 = 0; t4 < 4; ++t4)
#pragma unroll
    for (int r = 0; r < 4; ++r) {
      const int j = 16 * t4 + 4 * q + r;
      bsc[t4][r] = (bi[j] + bh[j]) * K2LOG2E;
    }

  const fx4 z4 = {0.f, 0.f, 0.f, 0.f};
  U8 hA, hB;                       // own state h_wv(t-1): hA=(j 0..31), hB=(j 32..63)
  hA.v = z8; hB.v = z8;

  // ---------- wave-0 x buffer: 4 t's of this interval (raw fx4) ----------
  const float* xr = x + (size_t)(bbase + m15) * (80 * 32) + 8 * q;
  fx4 xb0[4], xb1[4];
  if (wv == 0) {
#pragma unroll
    for (int jj = 0; jj < 4; ++jj) {          // preload t = 0..3
      xb0[jj] = *(const fx4*)(xr + jj * 32);
      xb1[jj] = *(const fx4*)(xr + jj * 32 + 4);
    }
  }

  for (int m = 0; m < 22; ++m) {
    const int lt0 = 4 * (m - wv);             // first t of this interval
    if (0 <= lt0 && lt0 <= 76) {              // wave-uniform
      // ---- interval top: gather all 4 inputs ----
      s16x8 inA[4], inB[4];
      if (wv == 0) {
#pragma unroll
        for (int jj = 0; jj < 4; ++jj) {
          union { unsigned u[4]; s16x8 v; } xp;
          xp.u[0] = pk2bf(xb0[jj][0], xb0[jj][1]);
          xp.u[1] = pk2bf(xb0[jj][2], xb0[jj][3]);
          xp.u[2] = pk2bf(xb1[jj][0], xb1[jj][1]);
          xp.u[3] = pk2bf(xb1[jj][2], xb1[jj][3]);
          inA[jj] = xp.v; inB[jj] = z8;
        }
        // refill for next interval (t = lt0+4 .. lt0+7, clamped); issued now,
        // consumed at NEXT interval top -> full interval to land
#pragma unroll
        for (int jj = 0; jj < 4; ++jj) {
          const int tt = (lt0 + 4 + jj <= 79) ? lt0 + 4 + jj : 79;
          xb0[jj] = *(const fx4*)(xr + tt * 32);
          xb1[jj] = *(const fx4*)(xr + tt * 32 + 4);
        }
      } else {
#pragma unroll
        for (int jj = 0; jj < 4; ++jj) {
          const short* up = &hb[wv - 1][(lt0 + jj) & 7][m15][8 * q];
          inA[jj] = *(const s16x8*)(up);
          inB[jj] = *(const s16x8*)(up + 32);
        }
      }
      // ---- 4 sequential steps (publish DEFERRED to interval end) ----
      s16x4 sv[4][4];                          // per-step tanh'd tiles (regs)
#pragma unroll
      for (int jj = 0; jj < 4; ++jj) {
        fx4 acc[4];
#pragma unroll
        for (int t4 = 0; t4 < 4; ++t4) acc[t4] = MFMA32(wiA[t4], inA[jj], z4);
        if (wv) {
#pragma unroll
          for (int t4 = 0; t4 < 4; ++t4) acc[t4] = MFMA32(wiB[t4], inB[jj], acc[t4]);
        }
#pragma unroll
        for (int t4 = 0; t4 < 4; ++t4) acc[t4] = MFMA32(wh32[t4][0], hA.v, acc[t4]);
#pragma unroll
        for (int t4 = 0; t4 < 4; ++t4) acc[t4] = MFMA32(wh32[t4][1], hB.v, acc[t4]);
        // tanh -> new own state; NO LDS traffic inside the serial section
        U8 nA, nB;
#pragma unroll
        for (int t4 = 0; t4 < 4; ++t4) {
          s16x4 hv = tanh_pack(acc[t4], bsc[t4]);
          sv[jj][t4] = hv;
          if (t4 < 2) nA.h[t4] = hv; else nB.h[t4 - 2] = hv;
        }
        hA = nA; hB = nB;
      }
      // ---- batched publish for downstream (layers 0,1 only): overlaps the
      // barrier drain; readers consume only after the next __syncthreads ----
      if (wv < 2) {
#pragma unroll
        for (int jj = 0; jj < 4; ++jj) {
          short* wb = &hb[wv][(lt0 + jj) & 7][m15][4 * q];
#pragma unroll
          for (int t4 = 0; t4 < 4; ++t4)
            *(s16x4*)(wb + 16 * t4) = sv[jj][t4];
        }
      }
    }
    __syncthreads();                          // ONE barrier per 4-step interval
  }

  // ---------- FC head: wave 2's state == h2(79), j = 16*kf + 4*q + i ----------
  if (wv == 2) {
    float sv2 = 0.f;
#pragma unroll
    for (int kf = 0; kf < 4; ++kf) {
      const s16x4 hh = (kf < 2) ? hA.h[kf] : hB.h[kf - 2];
#pragma unroll
      for (int i = 0; i < 4; ++i)
        sv2 += bf2f(hh[i]) * Wfc[16 * kf + 4 * q + i];
    }
    sv2 += __shfl_xor(sv2, 16, 64);
    sv2 += __shfl_xor(sv2, 32, 64);
    if (ln < 16) out[bbase + ln] = sv2 + bfc[0];
  }
}

extern "C" void kernel_launch(void* const* d_in, const int* in_sizes, int n_in,
                              void* d_out, int out_size, void* d_ws, size_t ws_size,
                              hipStream_t stream) {
  const float* x    = (const float*)d_in[0];
  const float* Wih0 = (const float*)d_in[1];
  const float* Whh0 = (const float*)d_in[2];
  const float* bih0 = (const float*)d_in[3];
  const float* bhh0 = (const float*)d_in[4];
  const float* Wih1 = (const float*)d_in[5];
  const float* Whh1 = (const float*)d_in[6];
  const float* bih1 = (const float*)d_in[7];
  const float* bhh1 = (const float*)d_in[8];
  const float* Wih2 = (const float*)d_in[9];
  const float* Whh2 = (const float*)d_in[10];
  const float* bih2 = (const float*)d_in[11];
  const float* bhh2 = (const float*)d_in[12];
  const float* Wfc  = (const float*)d_in[13];
  const float* bfc  = (const float*)d_in[14];

  // 512 blocks x 192 thr (3 waves = 3 pipelined layers), 16 batch rows/block:
  // 2 blocks/CU, 1.5 waves/SIMD (R12 config - best measured).
  rnn3_prcp<<<dim3(512), dim3(192), 0, stream>>>(
      x, Wih0, Whh0, bih0, bhh0, Wih1, Whh1, bih1, bhh1,
      Wih2, Whh2, bih2, bhh2, Wfc, bfc, (float*)d_out);
}